// Round 11
// baseline (1479.279 us; speedup 1.0000x reference)
//
#include <hip/hip_runtime.h>
#include <math.h>

#define SL 1024
#define NW 256

typedef _Float16 half8 __attribute__((ext_vector_type(8)));
typedef _Float16 half2t __attribute__((ext_vector_type(2)));
typedef float f32x4 __attribute__((ext_vector_type(4)));

__device__ __forceinline__ float rcp_f(float v) { return __builtin_amdgcn_rcpf(v); }

// mfma_f32_16x16x32_f16 (layouts verified r2-r10, builtins only):
//   A: lane row m = lane&15, k = (lane>>4)*8+e;  B: lane col n = lane&15, same k
//   D: lane col n = lane&15, row m = (lane>>4)*4 + reg
// Broadcast-A (lane reads h row lane&1): on EVERY lane, acc regs 0,1 = batch rows 0,1.
// 8 waves, 2/SIMD. Wave w owns 6 gh tiles (gate q, tile 2w+j) + 1 head MFMA
// on its k-slice [32w,32w+32) (B7 col0 = wd) -> replaces the serial butterfly.
// A fragments prefetched post-barrier; SrcC of kt=0 is loop-invariant zc.
__global__ __launch_bounds__(512, 2) void gru_mfma_kernel(
    const float* __restrict__ x, const float* __restrict__ w_ih,
    const float* __restrict__ w_hh, const float* __restrict__ b_ih,
    const float* __restrict__ b_hh, const float* __restrict__ fc_w,
    const float* __restrict__ fc_b, float* __restrict__ out)
{
    const int tid  = threadIdx.x;
    const int w    = tid >> 6;     // wave 0..7
    const int lane = tid & 63;
    const int c    = lane & 15;
    const int g    = lane >> 4;    // k-group for fragments
    const int gl   = g & 1;        // tile parity for gate eval (g>=2 duplicate)
    const int row0 = blockIdx.x * 2;

    __shared__ float    x_lds[2][1026];                   // m values; idx0 = 0.5 (t=-1)
    __shared__ __align__(16) _Float16 h_lds[2][2][288];   // dbuf, 2 batch rows
    __shared__ float    dpart[SL][8][2];                  // per-step per-wave head partials
    __shared__ float    wsum[8][2];

    for (int i = tid; i < 2 * SL; i += 512) {
        int b = i >> 10, j = i & (SL - 1);
        x_lds[b][1 + j] = (x[(size_t)(row0 + b) * SL + j] + 1.0f) * 0.5f;
    }
    if (tid < 2) x_lds[tid][0] = 0.5f;
    for (int i = tid; i < 2 * 2 * 288; i += 512)
        ((_Float16*)h_lds)[i] = (_Float16)0.0f;

    // persistent B fragments: f = q*2 + j -> w_hh row q*256 + (2w+j)*16 + c
    half8 Bf[6][8];
    #pragma unroll
    for (int f = 0; f < 6; ++f) {
        const int q = f >> 1, j = f & 1;
        const int urow = q * NW + (2 * w + j) * 16 + c;
        #pragma unroll
        for (int kt = 0; kt < 8; ++kt) {
            const float* p = w_hh + (size_t)urow * NW + kt * 32 + g * 8;
            float4 lo = *(const float4*)p;
            float4 hi = *(const float4*)(p + 4);
            half8 hb;
            hb[0] = (_Float16)lo.x; hb[1] = (_Float16)lo.y;
            hb[2] = (_Float16)lo.z; hb[3] = (_Float16)lo.w;
            hb[4] = (_Float16)hi.x; hb[5] = (_Float16)hi.y;
            hb[6] = (_Float16)hi.z; hb[7] = (_Float16)hi.w;
            Bf[f][kt] = hb;
        }
    }

    // head fragment: wave w's k-slice; col 0 (lanes c==0) = wd = fc_w[0]-fc_w[1]
    half8 B7 = (half8)(_Float16)0.0f;
    if (c == 0) {
        #pragma unroll
        for (int e = 0; e < 8; ++e) {
            const int k = w * 32 + g * 8 + e;
            B7[e] = (_Float16)(fc_w[k] - fc_w[NW + k]);
        }
    }

    // gate constants for THIS lane's unit u = 32w + 16gl + c (f16-packed)
    const int u = 32 * w + 16 * gl + c;
    half2t pkr, pkz, pkn;
    {
        float w0, w1;
        w0 = w_ih[2 * u]; w1 = w_ih[2 * u + 1];
        pkr[0] = (_Float16)(w1 + b_ih[u] + b_hh[u]);
        pkr[1] = (_Float16)(w0 - w1);
        w0 = w_ih[2 * (NW + u)]; w1 = w_ih[2 * (NW + u) + 1];
        pkz[0] = (_Float16)(w1 + b_ih[NW + u] + b_hh[NW + u]);
        pkz[1] = (_Float16)(w0 - w1);
        w0 = w_ih[2 * (2 * NW + u)]; w1 = w_ih[2 * (2 * NW + u) + 1];
        pkn[0] = (_Float16)(w1 + b_ih[2 * NW + u]);
        pkn[1] = (_Float16)(w0 - w1);
    }
    const float bhn = b_hh[2 * NW + u];
    const float bd  = fc_b[0] - fc_b[1];

    const f32x4 zc = {0.f, 0.f, 0.f, 0.f};   // loop-invariant SrcC zero
    float h0 = 0.f, h1 = 0.f;

    __syncthreads();

    // prefetch A fragments (t = 0 buffer) + head slice
    half8 A0[8], Ah;
    #pragma unroll
    for (int kt = 0; kt < 8; ++kt)
        A0[kt] = *(const half8*)&h_lds[0][lane & 1][kt * 32 + g * 8];
    Ah = *(const half8*)&h_lds[0][lane & 1][w * 32 + g * 8];

    #pragma unroll 1
    for (int t = 0; t < SL; ++t) {
        const int nxt = (t & 1) ^ 1;

        f32x4 acc[6];
        #pragma unroll
        for (int f = 0; f < 6; ++f)
            acc[f] = __builtin_amdgcn_mfma_f32_16x16x32_f16(A0[0], Bf[f][0], zc, 0, 0, 0);
        #pragma unroll
        for (int kt = 1; kt < 8; ++kt) {
            #pragma unroll
            for (int f = 0; f < 6; ++f)
                acc[f] = __builtin_amdgcn_mfma_f32_16x16x32_f16(A0[kt], Bf[f][kt], acc[f], 0, 0, 0);
        }
        // head partial on this wave's k-slice (uses h_t -> d_{t-1}, stored shifted)
        f32x4 acc7 = __builtin_amdgcn_mfma_f32_16x16x32_f16(Ah, B7, zc, 0, 0, 0);

        const float m0 = x_lds[0][t];
        const float m1 = x_lds[1][t];

        // this lane's gate inputs: tile parity gl via cndmask, batch row = reg
        const float ar0 = gl ? acc[1][0] : acc[0][0];
        const float ar1 = gl ? acc[1][1] : acc[0][1];
        const float az0 = gl ? acc[3][0] : acc[2][0];
        const float az1 = gl ? acc[3][1] : acc[2][1];
        const float an0 = gl ? acc[5][0] : acc[4][0];
        const float an1 = gl ? acc[5][1] : acc[4][1];

        const float cmr = (float)pkr[0], cdr = (float)pkr[1];
        const float cmz = (float)pkz[0], cdz = (float)pkz[1];
        const float cmn = (float)pkn[0], cdn = (float)pkn[1];

        const float vr0 = ar0 + fmaf(m0, cdr, cmr);
        const float rr0 = rcp_f(1.f + __expf(-vr0));
        const float vz0 = az0 + fmaf(m0, cdz, cmz);
        const float zz0 = rcp_f(1.f + __expf(-vz0));
        const float un0 = fmaf(rr0, an0 + bhn, fmaf(m0, cdn, cmn));
        const float ng0 = fmaf(-2.f, rcp_f(1.f + __expf(2.f * un0)), 1.f);
        const float hn0 = fmaf(zz0, h0 - ng0, ng0);
        const float vr1 = ar1 + fmaf(m1, cdr, cmr);
        const float rr1 = rcp_f(1.f + __expf(-vr1));
        const float vz1 = az1 + fmaf(m1, cdz, cmz);
        const float zz1 = rcp_f(1.f + __expf(-vz1));
        const float un1 = fmaf(rr1, an1 + bhn, fmaf(m1, cdn, cmn));
        const float ng1 = fmaf(-2.f, rcp_f(1.f + __expf(2.f * un1)), 1.f);
        const float hn1 = fmaf(zz1, h1 - ng1, ng1);
        h0 = hn0; h1 = hn1;

        if (g < 2) {
            h_lds[nxt][0][u] = (_Float16)hn0;
            h_lds[nxt][1][u] = (_Float16)hn1;
        }
        if (lane == 0 && t != 0) {
            dpart[t - 1][w][0] = acc7[0];
            dpart[t - 1][w][1] = acc7[1];
        }
        __syncthreads();

        // prefetch next step's fragments (latency overlaps loop tail)
        #pragma unroll
        for (int kt = 0; kt < 8; ++kt)
            A0[kt] = *(const half8*)&h_lds[nxt][lane & 1][kt * 32 + g * 8];
        Ah = *(const half8*)&h_lds[nxt][lane & 1][w * 32 + g * 8];
    }

    // epilogue: d_{SL-1} from h_SL (prefetched Ah is h_lds[0] = h_SL)
    {
        f32x4 accE = __builtin_amdgcn_mfma_f32_16x16x32_f16(Ah, B7, zc, 0, 0, 0);
        if (lane == 0) {
            dpart[SL - 1][w][0] = accE[0];
            dpart[SL - 1][w][1] = accE[1];
        }
    }
    __syncthreads();

    // post-loop: softplus over all steps, block reduction
    float lpp0 = 0.f, lpp1 = 0.f;
    #pragma unroll 1
    for (int t = tid; t < SL; t += 512) {
        float d0 = bd, d1 = bd;
        #pragma unroll
        for (int q = 0; q < 8; ++q) { d0 += dpart[t][q][0]; d1 += dpart[t][q][1]; }
        const float u0 = (x_lds[0][t + 1] > 0.5f) ? -d0 : d0;
        const float u1 = (x_lds[1][t + 1] > 0.5f) ? -d1 : d1;
        lpp0 -= fmaxf(u0, 0.f) + __logf(1.f + __expf(-fabsf(u0)));
        lpp1 -= fmaxf(u1, 0.f) + __logf(1.f + __expf(-fabsf(u1)));
    }
    #pragma unroll
    for (int s = 1; s < 64; s <<= 1) {
        lpp0 += __shfl_xor(lpp0, s);
        lpp1 += __shfl_xor(lpp1, s);
    }
    if (lane == 0) { wsum[w][0] = lpp0; wsum[w][1] = lpp1; }
    __syncthreads();
    if (tid < 2) {
        float s = 0.f;
        #pragma unroll
        for (int q = 0; q < 8; ++q) s += wsum[q][tid];
        out[row0 + tid] = s;
    }
}

extern "C" void kernel_launch(void* const* d_in, const int* in_sizes, int n_in,
                              void* d_out, int out_size, void* d_ws, size_t ws_size,
                              hipStream_t stream) {
    const float* x    = (const float*)d_in[0];
    const float* w_ih = (const float*)d_in[1];
    const float* w_hh = (const float*)d_in[2];
    const float* b_ih = (const float*)d_in[3];
    const float* b_hh = (const float*)d_in[4];
    const float* fc_w = (const float*)d_in[5];
    const float* fc_b = (const float*)d_in[6];
    gru_mfma_kernel<<<256, 512, 0, stream>>>(
        x, w_ih, w_hh, b_ih, b_hh, fc_w, fc_b, (float*)d_out);
}

// Round 13
// 1081.270 us; speedup vs baseline: 1.3681x; 1.3681x over previous
//
#include <hip/hip_runtime.h>
#include <math.h>

#define SL 1024
#define NW 256

typedef _Float16 half8 __attribute__((ext_vector_type(8)));
typedef _Float16 half2t __attribute__((ext_vector_type(2)));
typedef float f32x4 __attribute__((ext_vector_type(4)));

__device__ __forceinline__ float rcp_f(float v) { return __builtin_amdgcn_rcpf(v); }

// mfma_f32_16x16x32_f16 (layouts verified r2-r11, builtins only):
//   A: lane row m = lane&15, k = (lane>>4)*8+e;  B: lane col n = lane&15, same k
//   D: lane col n = lane&15, row m = (lane>>4)*4 + reg
// Broadcast-A (lane reads h row lane&1): on EVERY lane, acc regs 0,1 = batch rows 0,1.
// 8 waves, 2/SIMD (r10 register-saturated base; r11 lesson: +48 regs spills,
// so only +12 here). kt order PERMUTED per wave: ktp = (w+j)&7, Bf[f][j]
// loaded to match -> j=0 is the wave's own k-slice, so the head-MFMA uses the
// j=0 A-fragment UNCONDITIONALLY (r11-proven form; r12's runtime-predicated
// MFMA miscompiled -> banned). Butterfly deleted.
__global__ __launch_bounds__(512, 2) void gru_mfma_kernel(
    const float* __restrict__ x, const float* __restrict__ w_ih,
    const float* __restrict__ w_hh, const float* __restrict__ b_ih,
    const float* __restrict__ b_hh, const float* __restrict__ fc_w,
    const float* __restrict__ fc_b, float* __restrict__ out)
{
    const int tid  = threadIdx.x;
    const int w    = tid >> 6;     // wave 0..7
    const int lane = tid & 63;
    const int c    = lane & 15;
    const int g    = lane >> 4;    // k-group for fragments
    const int gl   = g & 1;        // tile parity for gate eval (g>=2 duplicate)
    const int row0 = blockIdx.x * 2;

    __shared__ float    x_lds[2][1026];                   // m values; idx0 = 0.5 (t=-1)
    __shared__ __align__(16) _Float16 h_lds[2][2][288];   // dbuf, 2 batch rows
    __shared__ float    dpart[SL][8][2];                  // per-step per-wave head partials
    __shared__ float    wsum[8][2];

    for (int i = tid; i < 2 * SL; i += 512) {
        int b = i >> 10, j = i & (SL - 1);
        x_lds[b][1 + j] = (x[(size_t)(row0 + b) * SL + j] + 1.0f) * 0.5f;
    }
    if (tid < 2) x_lds[tid][0] = 0.5f;
    for (int i = tid; i < 2 * 2 * 288; i += 512)
        ((_Float16*)h_lds)[i] = (_Float16)0.0f;

    // persistent B fragments, kt-permuted: Bf[f][j] = k-slice ktp=(w+j)&7
    // f = q*2 + jt -> w_hh row q*256 + (2w+jt)*16 + c
    half8 Bf[6][8];
    #pragma unroll
    for (int f = 0; f < 6; ++f) {
        const int q = f >> 1, jt = f & 1;
        const int urow = q * NW + (2 * w + jt) * 16 + c;
        #pragma unroll
        for (int j = 0; j < 8; ++j) {
            const int ktp = (w + j) & 7;
            const float* p = w_hh + (size_t)urow * NW + ktp * 32 + g * 8;
            float4 lo = *(const float4*)p;
            float4 hi = *(const float4*)(p + 4);
            half8 hb;
            hb[0] = (_Float16)lo.x; hb[1] = (_Float16)lo.y;
            hb[2] = (_Float16)lo.z; hb[3] = (_Float16)lo.w;
            hb[4] = (_Float16)hi.x; hb[5] = (_Float16)hi.y;
            hb[6] = (_Float16)hi.z; hb[7] = (_Float16)hi.w;
            Bf[f][j] = hb;
        }
    }

    // head fragment: wave w's k-slice [32w,32w+32) (j=0 slice); col 0 = wd
    half8 B7 = (half8)(_Float16)0.0f;
    if (c == 0) {
        #pragma unroll
        for (int e = 0; e < 8; ++e) {
            const int k = w * 32 + g * 8 + e;
            B7[e] = (_Float16)(fc_w[k] - fc_w[NW + k]);
        }
    }

    // gate constants for THIS lane's unit u = 32w + 16gl + c (f16-packed)
    const int u = 32 * w + 16 * gl + c;
    half2t pkr, pkz, pkn;
    {
        float w0, w1;
        w0 = w_ih[2 * u]; w1 = w_ih[2 * u + 1];
        pkr[0] = (_Float16)(w1 + b_ih[u] + b_hh[u]);
        pkr[1] = (_Float16)(w0 - w1);
        w0 = w_ih[2 * (NW + u)]; w1 = w_ih[2 * (NW + u) + 1];
        pkz[0] = (_Float16)(w1 + b_ih[NW + u] + b_hh[NW + u]);
        pkz[1] = (_Float16)(w0 - w1);
        w0 = w_ih[2 * (2 * NW + u)]; w1 = w_ih[2 * (2 * NW + u) + 1];
        pkn[0] = (_Float16)(w1 + b_ih[2 * NW + u]);
        pkn[1] = (_Float16)(w0 - w1);
    }
    const float bhn = b_hh[2 * NW + u];
    const float bd  = fc_b[0] - fc_b[1];

    const f32x4 zc = {0.f, 0.f, 0.f, 0.f};   // loop-invariant SrcC zero
    float h0 = 0.f, h1 = 0.f;

    __syncthreads();

    #pragma unroll 1
    for (int t = 0; t < SL; ++t) {
        const int cur = t & 1, nxt = cur ^ 1;

        f32x4 acc[6];
        f32x4 acc7;
        #pragma unroll
        for (int j = 0; j < 8; ++j) {
            const int ktp = (w + j) & 7;
            half8 A = *(const half8*)&h_lds[cur][lane & 1][ktp * 32 + g * 8];
            if (j == 0) {
                #pragma unroll
                for (int f = 0; f < 6; ++f)
                    acc[f] = __builtin_amdgcn_mfma_f32_16x16x32_f16(A, Bf[f][0], zc, 0, 0, 0);
                // head on this wave's own k-slice (unconditional, r11-proven)
                acc7 = __builtin_amdgcn_mfma_f32_16x16x32_f16(A, B7, zc, 0, 0, 0);
            } else {
                #pragma unroll
                for (int f = 0; f < 6; ++f)
                    acc[f] = __builtin_amdgcn_mfma_f32_16x16x32_f16(A, Bf[f][j], acc[f], 0, 0, 0);
            }
        }

        const float m0 = x_lds[0][t];
        const float m1 = x_lds[1][t];

        // this lane's gate inputs: tile parity gl via cndmask, batch row = reg
        const float ar0 = gl ? acc[1][0] : acc[0][0];
        const float ar1 = gl ? acc[1][1] : acc[0][1];
        const float az0 = gl ? acc[3][0] : acc[2][0];
        const float az1 = gl ? acc[3][1] : acc[2][1];
        const float an0 = gl ? acc[5][0] : acc[4][0];
        const float an1 = gl ? acc[5][1] : acc[4][1];

        const float cmr = (float)pkr[0], cdr = (float)pkr[1];
        const float cmz = (float)pkz[0], cdz = (float)pkz[1];
        const float cmn = (float)pkn[0], cdn = (float)pkn[1];

        const float vr0 = ar0 + fmaf(m0, cdr, cmr);
        const float rr0 = rcp_f(1.f + __expf(-vr0));
        const float vz0 = az0 + fmaf(m0, cdz, cmz);
        const float zz0 = rcp_f(1.f + __expf(-vz0));
        const float un0 = fmaf(rr0, an0 + bhn, fmaf(m0, cdn, cmn));
        const float ng0 = fmaf(-2.f, rcp_f(1.f + __expf(2.f * un0)), 1.f);
        const float hn0 = fmaf(zz0, h0 - ng0, ng0);
        const float vr1 = ar1 + fmaf(m1, cdr, cmr);
        const float rr1 = rcp_f(1.f + __expf(-vr1));
        const float vz1 = az1 + fmaf(m1, cdz, cmz);
        const float zz1 = rcp_f(1.f + __expf(-vz1));
        const float un1 = fmaf(rr1, an1 + bhn, fmaf(m1, cdn, cmn));
        const float ng1 = fmaf(-2.f, rcp_f(1.f + __expf(2.f * un1)), 1.f);
        const float hn1 = fmaf(zz1, h1 - ng1, ng1);
        h0 = hn0; h1 = hn1;

        if (g < 2) {
            h_lds[nxt][0][u] = (_Float16)hn0;
            h_lds[nxt][1][u] = (_Float16)hn1;
        }
        // head partial used h_t -> it is d_{t-1}; store shifted
        if (lane == 0 && t != 0) {
            dpart[t - 1][w][0] = acc7[0];
            dpart[t - 1][w][1] = acc7[1];
        }

        __syncthreads();
    }

    // epilogue: d_{SL-1} from h_SL (in h_lds[0]; loop's final barrier passed)
    {
        half8 Ah = *(const half8*)&h_lds[0][lane & 1][w * 32 + g * 8];
        f32x4 accE = __builtin_amdgcn_mfma_f32_16x16x32_f16(Ah, B7, zc, 0, 0, 0);
        if (lane == 0) {
            dpart[SL - 1][w][0] = accE[0];
            dpart[SL - 1][w][1] = accE[1];
        }
    }
    __syncthreads();

    // post-loop: softplus over all steps, block reduction
    float lpp0 = 0.f, lpp1 = 0.f;
    #pragma unroll 1
    for (int t = tid; t < SL; t += 512) {
        float d0 = bd, d1 = bd;
        #pragma unroll
        for (int q = 0; q < 8; ++q) { d0 += dpart[t][q][0]; d1 += dpart[t][q][1]; }
        const float u0 = (x_lds[0][t + 1] > 0.5f) ? -d0 : d0;
        const float u1 = (x_lds[1][t + 1] > 0.5f) ? -d1 : d1;
        lpp0 -= fmaxf(u0, 0.f) + __logf(1.f + __expf(-fabsf(u0)));
        lpp1 -= fmaxf(u1, 0.f) + __logf(1.f + __expf(-fabsf(u1)));
    }
    #pragma unroll
    for (int s = 1; s < 64; s <<= 1) {
        lpp0 += __shfl_xor(lpp0, s);
        lpp1 += __shfl_xor(lpp1, s);
    }
    if (lane == 0) { wsum[w][0] = lpp0; wsum[w][1] = lpp1; }
    __syncthreads();
    if (tid < 2) {
        float s = 0.f;
        #pragma unroll
        for (int q = 0; q < 8; ++q) s += wsum[q][tid];
        out[row0 + tid] = s;
    }
}

extern "C" void kernel_launch(void* const* d_in, const int* in_sizes, int n_in,
                              void* d_out, int out_size, void* d_ws, size_t ws_size,
                              hipStream_t stream) {
    const float* x    = (const float*)d_in[0];
    const float* w_ih = (const float*)d_in[1];
    const float* w_hh = (const float*)d_in[2];
    const float* b_ih = (const float*)d_in[3];
    const float* b_hh = (const float*)d_in[4];
    const float* fc_w = (const float*)d_in[5];
    const float* fc_b = (const float*)d_in[6];
    gru_mfma_kernel<<<256, 512, 0, stream>>>(
        x, w_ih, w_hh, b_ih, b_hh, fc_w, fc_b, (float*)d_out);
}

// Round 14
// 1059.604 us; speedup vs baseline: 1.3961x; 1.0204x over previous
//
#include <hip/hip_runtime.h>
#include <math.h>

#define SL 1024
#define NW 256

typedef _Float16 half8 __attribute__((ext_vector_type(8)));
typedef _Float16 half2t __attribute__((ext_vector_type(2)));
typedef float f32x4 __attribute__((ext_vector_type(4)));

__device__ __forceinline__ float rcp_f(float v) { return __builtin_amdgcn_rcpf(v); }

// mfma_f32_16x16x32_f16 (layouts verified r2-r13, builtins only):
//   A: lane row m = lane&15, k = (lane>>4)*8+e;  B: lane col n = lane&15, same k
//   D: lane col n = lane&15, row m = (lane>>4)*4 + reg
// Broadcast-A (lane reads h row lane&1): acc regs 0,1 = batch rows 0,1.
// 8 waves, 2/SIMD. kt permuted: ktp=(w+j)&7; Bf[f][j] matches -> j=0 is the
// wave's OWN unit slice [32w,32w+32).
// NEW (r14): cross-step pipelining -- after gates + own h-store, each wave
// fires j=0 (6 gh + 1 head) for step t+1 from its OWN slice of h_lds[nxt]
// BEFORE the barrier (intra-wave ds order; slice owned exclusively). Gates
// computed one-row-per-lane (row = g>>1; g>=2 lanes were pure duplicates).
__global__ __launch_bounds__(512, 2) void gru_mfma_kernel(
    const float* __restrict__ x, const float* __restrict__ w_ih,
    const float* __restrict__ w_hh, const float* __restrict__ b_ih,
    const float* __restrict__ b_hh, const float* __restrict__ fc_w,
    const float* __restrict__ fc_b, float* __restrict__ out)
{
    const int tid  = threadIdx.x;
    const int w    = tid >> 6;     // wave 0..7
    const int lane = tid & 63;
    const int c    = lane & 15;
    const int g    = lane >> 4;    // k-group for fragments
    const int gl   = g & 1;        // unit sub-tile parity for gate eval
    const int row  = g >> 1;       // this lane's batch row for gate eval
    const int row0 = blockIdx.x * 2;

    __shared__ float    x_lds[2][1026];                   // m values; idx0 = 0.5 (t=-1)
    __shared__ __align__(16) _Float16 h_lds[2][2][288];   // dbuf, 2 batch rows
    __shared__ float    dpart[SL][8][2];                  // per-step per-wave head partials
    __shared__ float    wsum[8][2];

    for (int i = tid; i < 2 * SL; i += 512) {
        int b = i >> 10, j = i & (SL - 1);
        x_lds[b][1 + j] = (x[(size_t)(row0 + b) * SL + j] + 1.0f) * 0.5f;
    }
    if (tid < 2) x_lds[tid][0] = 0.5f;
    for (int i = tid; i < 2 * 2 * 288; i += 512)
        ((_Float16*)h_lds)[i] = (_Float16)0.0f;

    // persistent B fragments, kt-permuted: Bf[f][j] = k-slice ktp=(w+j)&7
    // f = q*2 + jt -> w_hh row q*256 + (2w+jt)*16 + c
    half8 Bf[6][8];
    #pragma unroll
    for (int f = 0; f < 6; ++f) {
        const int q = f >> 1, jt = f & 1;
        const int urow = q * NW + (2 * w + jt) * 16 + c;
        #pragma unroll
        for (int j = 0; j < 8; ++j) {
            const int ktp = (w + j) & 7;
            const float* p = w_hh + (size_t)urow * NW + ktp * 32 + g * 8;
            float4 lo = *(const float4*)p;
            float4 hi = *(const float4*)(p + 4);
            half8 hb;
            hb[0] = (_Float16)lo.x; hb[1] = (_Float16)lo.y;
            hb[2] = (_Float16)lo.z; hb[3] = (_Float16)lo.w;
            hb[4] = (_Float16)hi.x; hb[5] = (_Float16)hi.y;
            hb[6] = (_Float16)hi.z; hb[7] = (_Float16)hi.w;
            Bf[f][j] = hb;
        }
    }

    // head fragment: wave w's k-slice [32w,32w+32) (j=0 slice); col 0 = wd
    half8 B7 = (half8)(_Float16)0.0f;
    if (c == 0) {
        #pragma unroll
        for (int e = 0; e < 8; ++e) {
            const int k = w * 32 + g * 8 + e;
            B7[e] = (_Float16)(fc_w[k] - fc_w[NW + k]);
        }
    }

    // gate constants for THIS lane's unit u = 32w + 16gl + c (f16-packed)
    const int u = 32 * w + 16 * gl + c;
    half2t pkr, pkz, pkn;
    {
        float w0, w1;
        w0 = w_ih[2 * u]; w1 = w_ih[2 * u + 1];
        pkr[0] = (_Float16)(w1 + b_ih[u] + b_hh[u]);
        pkr[1] = (_Float16)(w0 - w1);
        w0 = w_ih[2 * (NW + u)]; w1 = w_ih[2 * (NW + u) + 1];
        pkz[0] = (_Float16)(w1 + b_ih[NW + u] + b_hh[NW + u]);
        pkz[1] = (_Float16)(w0 - w1);
        w0 = w_ih[2 * (2 * NW + u)]; w1 = w_ih[2 * (2 * NW + u) + 1];
        pkn[0] = (_Float16)(w1 + b_ih[2 * NW + u]);
        pkn[1] = (_Float16)(w0 - w1);
    }
    const float bhn = b_hh[2 * NW + u];
    const float bd  = fc_b[0] - fc_b[1];

    const f32x4 zc = {0.f, 0.f, 0.f, 0.f};   // loop-invariant SrcC zero
    float h0 = 0.f;                           // this lane's h[u] for its row

    // prologue: h_0 = 0 -> step-0's j=0 contribution and head are zero
    f32x4 acc[6];
    #pragma unroll
    for (int f = 0; f < 6; ++f) acc[f] = zc;
    f32x4 acc7 = zc;

    __syncthreads();

    #pragma unroll 1
    for (int t = 0; t < SL; ++t) {
        const int cur = t & 1, nxt = cur ^ 1;

        // store previous step's head partial (acc7 = wd . h_t = d_{t-1})
        if (lane == 0 && t != 0) {
            dpart[t - 1][w][0] = acc7[0];
            dpart[t - 1][w][1] = acc7[1];
        }

        // j = 1..7: other waves' slices (ready since last barrier)
        const _Float16* hb = &h_lds[cur][lane & 1][g * 8];
        #pragma unroll
        for (int j = 1; j < 8; ++j) {
            const int ktp = (w + j) & 7;
            half8 A = *(const half8*)(hb + ktp * 32);
            #pragma unroll
            for (int f = 0; f < 6; ++f)
                acc[f] = __builtin_amdgcn_mfma_f32_16x16x32_f16(A, Bf[f][j], acc[f], 0, 0, 0);
        }

        // gates: one row per lane (row = g>>1), static acc selection
        const float m  = x_lds[row][t];
        const float ar = row ? (gl ? acc[1][1] : acc[0][1]) : (gl ? acc[1][0] : acc[0][0]);
        const float az = row ? (gl ? acc[3][1] : acc[2][1]) : (gl ? acc[3][0] : acc[2][0]);
        const float an = row ? (gl ? acc[5][1] : acc[4][1]) : (gl ? acc[5][0] : acc[4][0]);

        const float cmr = (float)pkr[0], cdr = (float)pkr[1];
        const float cmz = (float)pkz[0], cdz = (float)pkz[1];
        const float cmn = (float)pkn[0], cdn = (float)pkn[1];

        const float vr = ar + fmaf(m, cdr, cmr);
        const float rr = rcp_f(1.f + __expf(-vr));
        const float vz = az + fmaf(m, cdz, cmz);
        const float zz = rcp_f(1.f + __expf(-vz));
        const float un = fmaf(rr, an + bhn, fmaf(m, cdn, cmn));
        const float ng = fmaf(-2.f, rcp_f(1.f + __expf(2.f * un)), 1.f);
        const float hn = fmaf(zz, h0 - ng, ng);
        h0 = hn;

        // own h-store (64 lanes cover units 32w..32w+31 x rows 0,1)
        h_lds[nxt][row][u] = (_Float16)hn;

        // pre-barrier j=0 for step t+1 from THIS wave's own slice of nxt
        // (intra-wave ds_write -> ds_read ordering; slice exclusively owned)
        {
            half8 A = *(const half8*)&h_lds[nxt][lane & 1][w * 32 + g * 8];
            #pragma unroll
            for (int f = 0; f < 6; ++f)
                acc[f] = __builtin_amdgcn_mfma_f32_16x16x32_f16(A, Bf[f][0], zc, 0, 0, 0);
            acc7 = __builtin_amdgcn_mfma_f32_16x16x32_f16(A, B7, zc, 0, 0, 0);
        }

        __syncthreads();
    }

    // final head partial: acc7 from iter SL-1 = wd . h_SL = d_{SL-1}
    if (lane == 0) {
        dpart[SL - 1][w][0] = acc7[0];
        dpart[SL - 1][w][1] = acc7[1];
    }
    __syncthreads();

    // post-loop: softplus over all steps, block reduction
    float lpp0 = 0.f, lpp1 = 0.f;
    #pragma unroll 1
    for (int t = tid; t < SL; t += 512) {
        float d0 = bd, d1 = bd;
        #pragma unroll
        for (int q = 0; q < 8; ++q) { d0 += dpart[t][q][0]; d1 += dpart[t][q][1]; }
        const float u0 = (x_lds[0][t + 1] > 0.5f) ? -d0 : d0;
        const float u1 = (x_lds[1][t + 1] > 0.5f) ? -d1 : d1;
        lpp0 -= fmaxf(u0, 0.f) + __logf(1.f + __expf(-fabsf(u0)));
        lpp1 -= fmaxf(u1, 0.f) + __logf(1.f + __expf(-fabsf(u1)));
    }
    #pragma unroll
    for (int s = 1; s < 64; s <<= 1) {
        lpp0 += __shfl_xor(lpp0, s);
        lpp1 += __shfl_xor(lpp1, s);
    }
    if (lane == 0) { wsum[w][0] = lpp0; wsum[w][1] = lpp1; }
    __syncthreads();
    if (tid < 2) {
        float s = 0.f;
        #pragma unroll
        for (int q = 0; q < 8; ++q) s += wsum[q][tid];
        out[row0 + tid] = s;
    }
}

extern "C" void kernel_launch(void* const* d_in, const int* in_sizes, int n_in,
                              void* d_out, int out_size, void* d_ws, size_t ws_size,
                              hipStream_t stream) {
    const float* x    = (const float*)d_in[0];
    const float* w_ih = (const float*)d_in[1];
    const float* w_hh = (const float*)d_in[2];
    const float* b_ih = (const float*)d_in[3];
    const float* b_hh = (const float*)d_in[4];
    const float* fc_w = (const float*)d_in[5];
    const float* fc_b = (const float*)d_in[6];
    gru_mfma_kernel<<<256, 512, 0, stream>>>(
        x, w_ih, w_hh, b_ih, b_hh, fc_w, fc_b, (float*)d_out);
}